// Round 10
// baseline (170.310 us; speedup 1.0000x reference)
//
#include <hip/hip_runtime.h>

#define HID 50
#define TSTEPS 512

// All lanes of a wave execute in lockstep (one instruction stream), so after
// tanh, lane k's hn register IS h[k], already "synchronized". Broadcast via
// v_readlane_b32 into SGPRs (literal lane index) and feed v_fma_f32 with its
// one allowed SGPR operand. The recurrence loop touches NO memory at all:
// no LDS queueing (the round-4/7 bottleneck: 8 waves/CU x 13 ds_read_b128
// per step ~70% LDS-pipe utilization -> queue-inflated latency in the serial
// chain), no write-ack, no barrier.
__device__ __forceinline__ float readlane_f32(float v, int lane) {
    union { float f; unsigned u; } a, r;
    a.f = v;
    r.u = __builtin_amdgcn_readlane(a.u, lane);
    return r.f;
}

// One wave per batch element; lane j owns h[j] and row j of W_hh in 50 VGPRs
// (pre-scaled by 2*log2e so tanh needs no input multiply). Scalar FMAs only
// (v_pk_fma_f32 measured half-rate, round 5). Grid fixed at 2048 waves =
// 2/SIMD -> waves_per_eu(2,2) for the full VGPR budget.
__global__ __launch_bounds__(64) __attribute__((amdgpu_waves_per_eu(2, 2)))
void rnn_fused(
    const float* __restrict__ x,      // [B, 512, 1]
    const float* __restrict__ W_ih,   // [50, 1]
    const float* __restrict__ W_hh,   // [50, 50]
    const float* __restrict__ b_ih,   // [50]
    const float* __restrict__ b_hh,   // [50]
    const float* __restrict__ W_fc,   // [1, 50]
    const float* __restrict__ b_fc,   // [1]
    float* __restrict__ out)          // [B, 1]
{
    const int b = blockIdx.x;
    const int j = threadIdx.x;        // 0..63; lanes 50..63 duplicate row 0
    const int jj = (j < HID) ? j : 0;
    const float SC = 2.8853900817779268f;   // 2*log2(e)

    float w[HID];
#pragma unroll
    for (int k = 0; k < HID; ++k) w[k] = W_hh[jj * HID + k] * SC;

    const float wih  = W_ih[jj] * SC;
    const float btot = (b_ih[jj] + b_hh[jj]) * SC;
    const float wfc  = (j < HID) ? W_fc[jj] : 0.0f;
    const float bfc  = b_fc[0];

    const float* xb = x + (size_t)b * TSTEPS;
    float xv = xb[j];                 // 64 timesteps of x, one per lane
    float hn = 0.0f;

    for (int c = 0; c < TSTEPS / 64; ++c) {
        float xv_next = 0.0f;
        if (c + 1 < TSTEPS / 64) xv_next = xb[(c + 1) * 64 + j];

        for (int g = 0; g < 8; ++g) {
#pragma unroll
            for (int ii = 0; ii < 8; ++ii) {
                const int t = g * 8 + ii;

                const float xt = readlane_f32(xv, t);       // uniform x[b][t]
                float a0 = fmaf(xt, wih, btot);             // fma(s,v,v)
                float a1 = 0.0f, a2 = 0.0f, a3 = 0.0f;

                // h broadcast: 50 readlanes -> SGPRs, 50 FMAs (SGPR operand).
                // Same 4-accumulator tree as rounds 4-7 -> bit-identical sum.
#pragma unroll
                for (int k = 0; k < 48; k += 4) {
                    a0 = fmaf(readlane_f32(hn, k + 0), w[k + 0], a0);
                    a1 = fmaf(readlane_f32(hn, k + 1), w[k + 1], a1);
                    a2 = fmaf(readlane_f32(hn, k + 2), w[k + 2], a2);
                    a3 = fmaf(readlane_f32(hn, k + 3), w[k + 3], a3);
                }
                a0 = fmaf(readlane_f32(hn, 48), w[48], a0);
                a1 = fmaf(readlane_f32(hn, 49), w[49], a1);
                const float z = (a0 + a1) + (a2 + a3);      // scaled by 2*log2e

                // tanh(s) = 1 - 2/(exp2(z)+1); saturates correctly at +-inf
                const float e = __builtin_amdgcn_exp2f(z);
                const float r = __builtin_amdgcn_rcpf(e + 1.0f);
                hn = fmaf(-2.0f, r, 1.0f);
            }
        }
        xv = xv_next;
    }

    // out[b] = sum_j h[j] * W_fc[j] + b_fc  (lanes >= 50 contribute 0)
    float pr = hn * wfc;
#pragma unroll
    for (int off = 32; off >= 1; off >>= 1) pr += __shfl_xor(pr, off);
    if (j == 0) out[b] = pr + bfc;
}

extern "C" void kernel_launch(void* const* d_in, const int* in_sizes, int n_in,
                              void* d_out, int out_size, void* d_ws, size_t ws_size,
                              hipStream_t stream) {
    (void)d_ws; (void)ws_size; (void)n_in; (void)out_size;
    const float* x    = (const float*)d_in[0];
    const float* W_ih = (const float*)d_in[1];
    const float* W_hh = (const float*)d_in[2];
    const float* b_ih = (const float*)d_in[3];
    const float* b_hh = (const float*)d_in[4];
    const float* W_fc = (const float*)d_in[5];
    const float* b_fc = (const float*)d_in[6];
    float* out = (float*)d_out;

    const int B = in_sizes[0] / TSTEPS;   // 2048
    rnn_fused<<<dim3(B), dim3(64), 0, stream>>>(x, W_ih, W_hh, b_ih, b_hh, W_fc, b_fc, out);
}